// Round 1
// baseline (13204.582 us; speedup 1.0000x reference)
//
#include <hip/hip_runtime.h>
#include <hip/hip_fp16.h>

#define TSTEPS 512
#define NBLK_RNN 256

typedef _Float16 f16x8 __attribute__((ext_vector_type(8)));
typedef float f32x4 __attribute__((ext_vector_type(4)));

__device__ __forceinline__ float tanh_fast(float x) {
  float e = __expf(2.0f * x);
  return 1.0f - 2.0f / (e + 1.0f);
}

// ---------------- fp32 -> fp16 convert (vectorized, grid-stride) ----------------
__global__ void k_cvt(const float* __restrict__ src, __half* __restrict__ dst, int n4) {
  int i = blockIdx.x * blockDim.x + threadIdx.x;
  int stride = gridDim.x * blockDim.x;
  for (; i < n4; i += stride) {
    float4 v = ((const float4*)src)[i];
    __half2* d = (__half2*)(dst + 4 * (size_t)i);
    d[0] = __floats2half2_rn(v.x, v.y);
    d[1] = __floats2half2_rn(v.z, v.w);
  }
}

// ---------------- embedding gather + layernorm (no affine) ----------------
__global__ void k_embln(const int* __restrict__ x, const float* __restrict__ emb,
                        float* __restrict__ xln) {
  int row = blockIdx.x;  // b*T + t
  int tok = x[row];
  const float4* src = (const float4*)(emb + (size_t)tok * 1024);
  float4 v = src[threadIdx.x];
  float s = v.x + v.y + v.z + v.w;
  float q = v.x * v.x + v.y * v.y + v.z * v.z + v.w * v.w;
#pragma unroll
  for (int off = 32; off >= 1; off >>= 1) {
    s += __shfl_xor(s, off);
    q += __shfl_xor(q, off);
  }
  __shared__ float sm[8];
  int wave = threadIdx.x >> 6;
  if ((threadIdx.x & 63) == 0) { sm[wave] = s; sm[wave + 4] = q; }
  __syncthreads();
  float st = sm[0] + sm[1] + sm[2] + sm[3];
  float qt = sm[4] + sm[5] + sm[6] + sm[7];
  float mean = st * (1.0f / 1024.0f);
  float var = qt * (1.0f / 1024.0f) - mean * mean;
  float rs = rsqrtf(var + 1e-5f);
  float4 o;
  o.x = (v.x - mean) * rs; o.y = (v.y - mean) * rs;
  o.z = (v.z - mean) * rs; o.w = (v.w - mean) * rs;
  ((float4*)(xln + (size_t)row * 1024))[threadIdx.x] = o;
}

// ---------------- persistent fused 2-layer RNN recurrence ----------------
// 256 blocks x 256 threads, 1 block/CU. Block owns 4 rows of h0 and 4 rows of h1.
// Waves 0-1 (part A): h0_s = tanh(Wih0*x_s + Whh0*h0_{s-1} + b).
// Waves 2-3 (part B): h1_{s-1} = tanh(Wih1*h0_{s-1} + Whh1*h1_{s-2} + b).
// One grid barrier per step (custom flag-array barrier, agent scope).
__global__ __launch_bounds__(256, 1) void k_rnn(
    const float* __restrict__ xln,
    const float* __restrict__ Wih0, const float* __restrict__ Whh0,
    const float* __restrict__ bih0, const float* __restrict__ bhh0,
    const float* __restrict__ Wih1, const float* __restrict__ Whh1,
    const float* __restrict__ bih1, const float* __restrict__ bhh1,
    float* ring, __half* __restrict__ h1seq, unsigned* slots) {
  const int tid = threadIdx.x;
  const int blk = blockIdx.x;
  const int part = tid >> 7;       // 0 = layer0, 1 = layer1
  const int b2 = (tid >> 5) & 3;
  const int g = tid & 31;          // k-group (lane stride 32 over k)
  const int b_lo = b2, b_hi = b2 + 4;
  const int row0 = blk * 4;

  const float* Wih = part ? Wih1 : Wih0;
  const float* Whh = part ? Whh1 : Whh0;
  const float* bih = part ? bih1 : bih0;
  const float* bhh = part ? bhh1 : bhh0;

  // weight-stationary registers: 4 rows x 64 k-values (k = g + 32*i)
  float wv[4][64];
  float bias[4];
#pragma unroll
  for (int r = 0; r < 4; ++r) {
    const float* wi = Wih + (size_t)(row0 + r) * 1024 + g;
    const float* wh = Whh + (size_t)(row0 + r) * 1024 + g;
#pragma unroll
    for (int i = 0; i < 32; ++i) wv[r][i] = wi[32 * i];
#pragma unroll
    for (int i = 0; i < 32; ++i) wv[r][32 + i] = wh[32 * i];
    bias[r] = bih[row0 + r] + bhh[row0 + r];
  }

  float* h0r = ring;          // [2][8][1024]
  float* h1r = ring + 16384;  // [2][8][1024]

  for (int s = 0; s <= TSTEPS; ++s) {
    const bool active = (part == 0) ? (s < TSTEPS) : (s >= 1);
    if (active) {
      const float *vL0, *vL1, *vR0, *vR1;
      bool doR;
      if (part == 0) {
        vL0 = xln + ((size_t)b_lo * TSTEPS + s) * 1024 + g;
        vL1 = xln + ((size_t)b_hi * TSTEPS + s) * 1024 + g;
        const float* h0p = h0r + ((s - 1) & 1) * 8192;
        vR0 = h0p + b_lo * 1024 + g;
        vR1 = h0p + b_hi * 1024 + g;
        doR = (s > 0);
      } else {
        const float* h0p = h0r + ((s - 1) & 1) * 8192;
        vL0 = h0p + b_lo * 1024 + g;
        vL1 = h0p + b_hi * 1024 + g;
        const float* h1p = h1r + (s & 1) * 8192;  // parity of s-2 == parity of s
        vR0 = h1p + b_lo * 1024 + g;
        vR1 = h1p + b_hi * 1024 + g;
        doR = (s > 1);
      }
      float acc[4][2];
#pragma unroll
      for (int r = 0; r < 4; ++r) { acc[r][0] = 0.f; acc[r][1] = 0.f; }
#pragma unroll
      for (int i = 0; i < 32; ++i) {
        float v0 = vL0[32 * i];
        float v1 = vL1[32 * i];
#pragma unroll
        for (int r = 0; r < 4; ++r) {
          acc[r][0] += wv[r][i] * v0;
          acc[r][1] += wv[r][i] * v1;
        }
      }
      if (doR) {
#pragma unroll
        for (int i = 0; i < 32; ++i) {
          float v0 = vR0[32 * i];
          float v1 = vR1[32 * i];
#pragma unroll
          for (int r = 0; r < 4; ++r) {
            acc[r][0] += wv[r][32 + i] * v0;
            acc[r][1] += wv[r][32 + i] * v1;
          }
        }
      }
      // reduce partial dots across the 32 k-group lanes
#pragma unroll
      for (int r = 0; r < 4; ++r)
#pragma unroll
        for (int c = 0; c < 2; ++c) {
          float v = acc[r][c];
          v += __shfl_xor(v, 1);
          v += __shfl_xor(v, 2);
          v += __shfl_xor(v, 4);
          v += __shfl_xor(v, 8);
          v += __shfl_xor(v, 16);
          acc[r][c] = v;
        }
      if (g == 0) {
        if (part == 0) {
          float* dst = h0r + (s & 1) * 8192;
#pragma unroll
          for (int r = 0; r < 4; ++r) {
            dst[b_lo * 1024 + row0 + r] = tanh_fast(acc[r][0] + bias[r]);
            dst[b_hi * 1024 + row0 + r] = tanh_fast(acc[r][1] + bias[r]);
          }
        } else {
          float* dst = h1r + ((s - 1) & 1) * 8192;
          const int t = s - 1;
#pragma unroll
          for (int r = 0; r < 4; ++r) {
            float hv0 = tanh_fast(acc[r][0] + bias[r]);
            float hv1 = tanh_fast(acc[r][1] + bias[r]);
            dst[b_lo * 1024 + row0 + r] = hv0;
            dst[b_hi * 1024 + row0 + r] = hv1;
            h1seq[((size_t)b_lo * TSTEPS + t) * 1024 + row0 + r] = __float2half(hv0);
            h1seq[((size_t)b_hi * TSTEPS + t) * 1024 + row0 + r] = __float2half(hv1);
          }
        }
      }
    }
    // ---- grid barrier: flush, post own slot, poll all 256 slots, invalidate ----
    __syncthreads();
    if (tid == 0) {
      __builtin_amdgcn_fence(__ATOMIC_RELEASE, "agent");
      __hip_atomic_store(&slots[blk], (unsigned)(s + 1), __ATOMIC_RELAXED,
                         __HIP_MEMORY_SCOPE_AGENT);
    }
    const unsigned tgt = (unsigned)(s + 1);
    while (__hip_atomic_load(&slots[tid], __ATOMIC_RELAXED,
                             __HIP_MEMORY_SCOPE_AGENT) < tgt) {}
    __builtin_amdgcn_fence(__ATOMIC_ACQUIRE, "agent");
    __syncthreads();
  }
}

// ---------------- fp16 MFMA GEMM: C[M,N] = A[M,K] * B[N,K]^T (+bias,relu) ----------------
// MODE 1: += bias, relu, store half. MODE 0: store float.
template <int MODE>
__global__ __launch_bounds__(256) void k_gemm(const __half* __restrict__ A,
                                              const __half* __restrict__ B,
                                              const float* __restrict__ bias,
                                              void* __restrict__ Cout, int M, int N,
                                              int K) {
  __shared__ __half As[128 * 32];
  __shared__ __half Bs[128 * 32];
  const int tid = threadIdx.x;
  const int m0 = blockIdx.y * 128;
  const int n0 = blockIdx.x * 128;
  const int lane = tid & 63;
  const int wave = tid >> 6;
  const int wy = wave >> 1, wx = wave & 1;
  const int fr = lane & 15, q = lane >> 4;

  const int srow = tid >> 1;
  const int skc = (tid & 1) * 16;
  const __half* Ag = A + (size_t)(m0 + srow) * K + skc;
  const __half* Bg = B + (size_t)(n0 + srow) * K + skc;
  __half* Asw = &As[srow * 32 + skc];
  __half* Bsw = &Bs[srow * 32 + skc];

  f32x4 acc[4][4];
#pragma unroll
  for (int i = 0; i < 4; ++i)
#pragma unroll
    for (int j = 0; j < 4; ++j) acc[i][j] = (f32x4){0.f, 0.f, 0.f, 0.f};

  for (int k0 = 0; k0 < K; k0 += 32) {
    int4 a0 = *(const int4*)Ag;
    int4 a1 = *(const int4*)(Ag + 8);
    int4 b0 = *(const int4*)Bg;
    int4 b1 = *(const int4*)(Bg + 8);
    *(int4*)Asw = a0;
    *(int4*)(Asw + 8) = a1;
    *(int4*)Bsw = b0;
    *(int4*)(Bsw + 8) = b1;
    __syncthreads();
    f16x8 af[4], bf[4];
#pragma unroll
    for (int i = 0; i < 4; ++i)
      af[i] = *(const f16x8*)&As[(wy * 64 + i * 16 + fr) * 32 + q * 8];
#pragma unroll
    for (int j = 0; j < 4; ++j)
      bf[j] = *(const f16x8*)&Bs[(wx * 64 + j * 16 + fr) * 32 + q * 8];
#pragma unroll
    for (int i = 0; i < 4; ++i)
#pragma unroll
      for (int j = 0; j < 4; ++j)
        acc[i][j] = __builtin_amdgcn_mfma_f32_16x16x32_f16(af[i], bf[j], acc[i][j], 0, 0, 0);
    __syncthreads();
    Ag += 32;
    Bg += 32;
  }

  // C/D layout: col = lane&15, row = (lane>>4)*4 + reg  [m89-verified]
  const int rb = q * 4;
#pragma unroll
  for (int i = 0; i < 4; ++i) {
#pragma unroll
    for (int j = 0; j < 4; ++j) {
      int col = n0 + wx * 64 + j * 16 + fr;
      float bv = 0.f;
      if (MODE == 1) bv = bias[col];
#pragma unroll
      for (int r = 0; r < 4; ++r) {
        int row = m0 + wy * 64 + i * 16 + rb + r;
        float v = acc[i][j][r];
        if (MODE == 1) {
          v = fmaxf(v + bv, 0.f);
          ((__half*)Cout)[(size_t)row * N + col] = __float2half(v);
        } else {
          ((float*)Cout)[(size_t)row * N + col] = v;
        }
      }
    }
  }
}

extern "C" void kernel_launch(void* const* d_in, const int* in_sizes, int n_in,
                              void* d_out, int out_size, void* d_ws, size_t ws_size,
                              hipStream_t stream) {
  const int* x = (const int*)d_in[0];
  const float* emb = (const float*)d_in[1];
  const float* Wih0 = (const float*)d_in[2];
  const float* Whh0 = (const float*)d_in[3];
  const float* bih0 = (const float*)d_in[4];
  const float* bhh0 = (const float*)d_in[5];
  const float* Wih1 = (const float*)d_in[6];
  const float* Whh1 = (const float*)d_in[7];
  const float* bih1 = (const float*)d_in[8];
  const float* bhh1 = (const float*)d_in[9];
  const float* Wlin = (const float*)d_in[10];
  const float* blin = (const float*)d_in[11];
  float* out = (float*)d_out;

  // workspace layout (bytes, all 16B-aligned)
  char* w = (char*)d_ws;
  __half* embh = (__half*)(w);                          // 32000*1024*2 = 65,536,000
  __half* wlinh = (__half*)(w + 65536000);              // 1024*1024*2  =  2,097,152
  float* xln = (float*)(w + 67633152);                  // 4096*1024*4  = 16,777,216
  __half* h1seq = (__half*)(w + 84410368);              // 8*512*1024*2 =  8,388,608
  __half* hrelu = (__half*)(w + 92798976);              // 4096*1024*2  =  8,388,608
  float* ring = (float*)(w + 101187584);                // 4*8192*4     =    131,072
  unsigned* slots = (unsigned*)(w + 101318656);         // 256*4 (+pad)
  (void)in_sizes; (void)n_in; (void)out_size; (void)ws_size;

  hipMemsetAsync(slots, 0, 1024, stream);
  k_cvt<<<1024, 256, 0, stream>>>(emb, embh, 32000 * 1024 / 4);
  k_cvt<<<256, 256, 0, stream>>>(Wlin, wlinh, 1024 * 1024 / 4);
  k_embln<<<4096, 256, 0, stream>>>(x, emb, xln);
  k_rnn<<<NBLK_RNN, 256, 0, stream>>>(xln, Wih0, Whh0, bih0, bhh0, Wih1, Whh1, bih1,
                                      bhh1, ring, h1seq, slots);
  k_gemm<1><<<dim3(1024 / 128, 4096 / 128), 256, 0, stream>>>(h1seq, wlinh, blin,
                                                              hrelu, 4096, 1024, 1024);
  k_gemm<0><<<dim3(32000 / 128, 4096 / 128), 256, 0, stream>>>(hrelu, embh, nullptr,
                                                               out, 4096, 32000, 1024);
}